// Round 7
// baseline (330.476 us; speedup 1.0000x reference)
//
#include <hip/hip_runtime.h>
#include <hip/hip_fp16.h>
#include <math.h>

#define N_NODES 65536
#define N_EDGES 1048576
#define HDIM 64
#define NCLS 10
#define NGRAPH 256
#define NLAYER 3
#define BN_EPS 1e-5f

// ---------------- degree count ----------------

__global__ __launch_bounds__(256) void deg_count_kernel(const int* __restrict__ dst,
                                                        unsigned* __restrict__ cnt) {
    int e = blockIdx.x * 256 + threadIdx.x;
    if (e < N_EDGES) atomicAdd(&cnt[dst[e]], 1u);
}

// ---------------- CSR build: exclusive scan (+ dis fused) ----------------

__global__ __launch_bounds__(256) void scan1_kernel(const unsigned* __restrict__ cnt,
                                                    unsigned* __restrict__ offsets,
                                                    unsigned* __restrict__ bsum,
                                                    float* __restrict__ dis) {
    __shared__ unsigned lds[256];
    int t = threadIdx.x, b = blockIdx.x;
    unsigned v = cnt[b * 256 + t];
    dis[b * 256 + t] = rsqrtf((float)(v + 1u));
    lds[t] = v;
    __syncthreads();
#pragma unroll
    for (int off = 1; off < 256; off <<= 1) {
        unsigned add = (t >= off) ? lds[t - off] : 0u;
        __syncthreads();
        lds[t] += add;
        __syncthreads();
    }
    offsets[b * 256 + t] = lds[t] - v;  // exclusive within block
    if (t == 255) bsum[b] = lds[255];
}

__global__ __launch_bounds__(256) void scan2_kernel(unsigned* __restrict__ bsum,
                                                    unsigned* __restrict__ carry,
                                                    unsigned* __restrict__ offsets) {
    __shared__ unsigned lds[256];
    int t = threadIdx.x;
    unsigned v = bsum[t];
    lds[t] = v;
    __syncthreads();
#pragma unroll
    for (int off = 1; off < 256; off <<= 1) {
        unsigned add = (t >= off) ? lds[t - off] : 0u;
        __syncthreads();
        lds[t] += add;
        __syncthreads();
    }
    carry[t] = lds[t] - v;  // exclusive
    if (t == 255) offsets[N_NODES] = lds[255];  // total = E
}

__global__ __launch_bounds__(256) void scan3_kernel(unsigned* __restrict__ offsets,
                                                    const unsigned* __restrict__ carry) {
    int i = blockIdx.x * 256 + threadIdx.x;
    if (i < N_NODES) offsets[i] += carry[i >> 8];
}

// fill: 4B payload (src only; dis folded into g16 payload, dis[dst] factored out)
__global__ __launch_bounds__(256) void fill_kernel(const int* __restrict__ ei,
                                                   const unsigned* __restrict__ offsets,
                                                   unsigned* __restrict__ cursor,
                                                   int* __restrict__ srcs) {
    int e = blockIdx.x * 256 + threadIdx.x;
    if (e < N_EDGES) {
        int s = ei[e];
        int d = ei[N_EDGES + e];
        unsigned r = atomicAdd(&cursor[d], 1u);
        srcs[offsets[d] + r] = s;
    }
}

// ---------------- g16 = fp16(x * dis) cast ----------------

__global__ __launch_bounds__(256) void cast_kernel(const float* __restrict__ x,
                                                   const float* __restrict__ dis,
                                                   __half* __restrict__ g16) {
    int i = blockIdx.x * 256 + threadIdx.x;  // float4 index, N*16 total
    float d = dis[i >> 4];
    float4 v = ((const float4*)x)[i];
    __half2 a = __floats2half2_rn(v.x * d, v.y * d);
    __half2 b = __floats2half2_rn(v.z * d, v.w * d);
    uint2 o;
    o.x = *(unsigned*)&a;
    o.y = *(unsigned*)&b;
    ((uint2*)g16)[i] = o;
}

// ---------------- pull aggregate: t[n] = dis[n]^2*h[n] + dis[n]*sum g16[src] ----------------
// one wave per node; lanes = 4 edge-slots x 16 feature lanes (4 halves each).
// main loop: 16 edge gathers (8B each) in flight per wave.

__global__ __launch_bounds__(256) void aggregate_kernel(const __half* __restrict__ g16,
                                                        const float* __restrict__ hin32,
                                                        const float* __restrict__ dis,
                                                        const unsigned* __restrict__ offsets,
                                                        const int* __restrict__ srcs,
                                                        float* __restrict__ t) {
    int n = (blockIdx.x * 256 + threadIdx.x) >> 6;
    int lane = threadIdx.x & 63;
    int eslot = lane >> 4;      // 0..3
    int fq = lane & 15;         // 4-half feature chunk index
    int e0 = (int)offsets[n];
    int e1 = (int)offsets[n + 1];

    const uint2* hv = (const uint2*)g16;  // 8B = 4 halves per chunk, 16 chunks per row

    float4 acc = make_float4(0.f, 0.f, 0.f, 0.f);
    int e = e0 + eslot;
    // unrolled x4: 16 edges in flight across the wave
    for (; e + 12 < e1; e += 16) {
        int s0 = srcs[e];
        int s1 = srcs[e + 4];
        int s2 = srcs[e + 8];
        int s3 = srcs[e + 12];
        uint2 r0 = hv[((size_t)s0 << 4) + fq];
        uint2 r1 = hv[((size_t)s1 << 4) + fq];
        uint2 r2 = hv[((size_t)s2 << 4) + fq];
        uint2 r3 = hv[((size_t)s3 << 4) + fq];
        {
            float2 lo = __half22float2(*(__half2*)&r0.x);
            float2 hi = __half22float2(*(__half2*)&r0.y);
            acc.x += lo.x; acc.y += lo.y; acc.z += hi.x; acc.w += hi.y;
        }
        {
            float2 lo = __half22float2(*(__half2*)&r1.x);
            float2 hi = __half22float2(*(__half2*)&r1.y);
            acc.x += lo.x; acc.y += lo.y; acc.z += hi.x; acc.w += hi.y;
        }
        {
            float2 lo = __half22float2(*(__half2*)&r2.x);
            float2 hi = __half22float2(*(__half2*)&r2.y);
            acc.x += lo.x; acc.y += lo.y; acc.z += hi.x; acc.w += hi.y;
        }
        {
            float2 lo = __half22float2(*(__half2*)&r3.x);
            float2 hi = __half22float2(*(__half2*)&r3.y);
            acc.x += lo.x; acc.y += lo.y; acc.z += hi.x; acc.w += hi.y;
        }
    }
    for (; e < e1; e += 4) {
        int sa = srcs[e];
        uint2 ra = hv[((size_t)sa << 4) + fq];
        float2 lo = __half22float2(*(__half2*)&ra.x);
        float2 hi = __half22float2(*(__half2*)&ra.y);
        acc.x += lo.x; acc.y += lo.y; acc.z += hi.x; acc.w += hi.y;
    }
    // reduce across edge slots (lanes l, l^16, l^32, l^48)
    acc.x += __shfl_xor(acc.x, 16); acc.y += __shfl_xor(acc.y, 16);
    acc.z += __shfl_xor(acc.z, 16); acc.w += __shfl_xor(acc.w, 16);
    acc.x += __shfl_xor(acc.x, 32); acc.y += __shfl_xor(acc.y, 32);
    acc.z += __shfl_xor(acc.z, 32); acc.w += __shfl_xor(acc.w, 32);
    if (eslot == 0) {
        float d = dis[n];
        float d2 = d * d;
        float4 sv = *(const float4*)&hin32[(size_t)n * HDIM + (fq << 2)];
        acc.x = acc.x * d + sv.x * d2;
        acc.y = acc.y * d + sv.y * d2;
        acc.z = acc.z * d + sv.z * d2;
        acc.w = acc.w * d + sv.w * d2;
        *(float4*)&t[(size_t)n * HDIM + (fq << 2)] = acc;
    }
}

// ---------------- GEMM t@W fused with bias+BN+ReLU+residual; writes h (f32) + g16 ----------------

__global__ __launch_bounds__(256) void gemm_kernel(const float* __restrict__ tin,
                                                   const float* __restrict__ W,
                                                   const float* __restrict__ bias,
                                                   const float* __restrict__ gamma,
                                                   const float* __restrict__ beta,
                                                   const float* __restrict__ mean,
                                                   const float* __restrict__ var,
                                                   const float* __restrict__ dis,
                                                   float* __restrict__ h,
                                                   __half* __restrict__ g16,
                                                   int has_res) {
    __shared__ float hs[64][68];
    __shared__ float ws[64 * 64];
    int tid = threadIdx.x;
    int row0 = blockIdx.x * 64;

    {
        const float4* Wv = (const float4*)W;
        float4* wsv = (float4*)ws;
#pragma unroll
        for (int i = 0; i < 4; ++i) wsv[tid + i * 256] = Wv[tid + i * 256];
    }
    {
        const float4* Hv = (const float4*)(tin + (size_t)row0 * HDIM);
#pragma unroll
        for (int i = 0; i < 4; ++i) {
            int idx = tid + i * 256;
            int r = idx >> 4;
            int c = (idx & 15) << 2;
            *(float4*)&hs[r][c] = Hv[idx];
        }
    }
    __syncthreads();

    int tx = tid & 15, ty = tid >> 4;
    float acc[4][4] = {};
#pragma unroll
    for (int kq = 0; kq < 16; ++kq) {
        int k = kq * 4;
        float4 a[4], b[4];
#pragma unroll
        for (int i = 0; i < 4; ++i) a[i] = *(const float4*)&hs[ty * 4 + i][k];
#pragma unroll
        for (int kk = 0; kk < 4; ++kk) b[kk] = *(const float4*)&ws[(k + kk) * 64 + tx * 4];
#pragma unroll
        for (int kk = 0; kk < 4; ++kk) {
            float b0 = b[kk].x, b1 = b[kk].y, b2 = b[kk].z, b3 = b[kk].w;
#pragma unroll
            for (int i = 0; i < 4; ++i) {
                float av = (kk == 0) ? a[i].x : (kk == 1) ? a[i].y : (kk == 2) ? a[i].z : a[i].w;
                acc[i][0] += av * b0;
                acc[i][1] += av * b1;
                acc[i][2] += av * b2;
                acc[i][3] += av * b3;
            }
        }
    }

    float4 b4 = ((const float4*)bias)[tx];
    float4 g4 = ((const float4*)gamma)[tx];
    float4 be4 = ((const float4*)beta)[tx];
    float4 m4 = ((const float4*)mean)[tx];
    float4 va4 = ((const float4*)var)[tx];
    float sc0 = g4.x * rsqrtf(va4.x + BN_EPS);
    float sc1 = g4.y * rsqrtf(va4.y + BN_EPS);
    float sc2 = g4.z * rsqrtf(va4.z + BN_EPS);
    float sc3 = g4.w * rsqrtf(va4.w + BN_EPS);
    float sh0 = (b4.x - m4.x) * sc0 + be4.x;
    float sh1 = (b4.y - m4.y) * sc1 + be4.y;
    float sh2 = (b4.z - m4.z) * sc2 + be4.z;
    float sh3 = (b4.w - m4.w) * sc3 + be4.w;

#pragma unroll
    for (int i = 0; i < 4; ++i) {
        int row = row0 + ty * 4 + i;
        float o0 = fmaxf(acc[i][0] * sc0 + sh0, 0.0f);
        float o1 = fmaxf(acc[i][1] * sc1 + sh1, 0.0f);
        float o2 = fmaxf(acc[i][2] * sc2 + sh2, 0.0f);
        float o3 = fmaxf(acc[i][3] * sc3 + sh3, 0.0f);
        if (has_res) {
            float4 r = *(const float4*)&h[(size_t)row * HDIM + tx * 4];
            o0 += r.x; o1 += r.y; o2 += r.z; o3 += r.w;
        }
        *(float4*)&h[(size_t)row * HDIM + tx * 4] = make_float4(o0, o1, o2, o3);
        float dd = dis[row];
        __half2 pa = __floats2half2_rn(o0 * dd, o1 * dd);
        __half2 pb = __floats2half2_rn(o2 * dd, o3 * dd);
        uint2 pk;
        pk.x = *(unsigned*)&pa;
        pk.y = *(unsigned*)&pb;
        *(uint2*)&g16[(size_t)row * HDIM + tx * 4] = pk;
    }
}

// ---------------- global mean pool over sorted batch ----------------

__device__ __forceinline__ int lower_bound_batch(const int* __restrict__ batch, int val) {
    int lo = 0, hi = N_NODES;
    while (lo < hi) {
        int mid = (lo + hi) >> 1;
        if (batch[mid] < val) lo = mid + 1; else hi = mid;
    }
    return lo;
}

__global__ __launch_bounds__(256) void pool_kernel(const float* __restrict__ h,
                                                   const int* __restrict__ batch,
                                                   float* __restrict__ repr) {
    int g = blockIdx.x;
    int start = lower_bound_batch(batch, g);
    int end = lower_bound_batch(batch, g + 1);
    int f = threadIdx.x & 63;
    int grp = threadIdx.x >> 6;
    float s0 = 0.f, s1 = 0.f, s2 = 0.f, s3 = 0.f;
    int n = start + grp;
    for (; n + 12 < end; n += 16) {
        s0 += h[(size_t)n * HDIM + f];
        s1 += h[(size_t)(n + 4) * HDIM + f];
        s2 += h[(size_t)(n + 8) * HDIM + f];
        s3 += h[(size_t)(n + 12) * HDIM + f];
    }
    for (; n < end; n += 4) s0 += h[(size_t)n * HDIM + f];
    float s = (s0 + s1) + (s2 + s3);
    __shared__ float red[4][64];
    red[grp][f] = s;
    __syncthreads();
    if (grp == 0) {
        float tot = red[0][f] + red[1][f] + red[2][f] + red[3][f];
        int cnt = end - start;
        repr[g * HDIM + f] = tot / (float)(cnt > 0 ? cnt : 1);
    }
}

// ---------------- classifier ----------------

__global__ __launch_bounds__(64) void classify_kernel(const float* __restrict__ repr,
                                                      const float* __restrict__ w1,
                                                      const float* __restrict__ b1,
                                                      const float* __restrict__ w2,
                                                      const float* __restrict__ b2,
                                                      float* __restrict__ out) {
    int g = blockIdx.x;
    int j = threadIdx.x;
    __shared__ float r[64], z[64], lg[NCLS];
    r[j] = repr[g * HDIM + j];
    __syncthreads();
    float acc = b1[j];
#pragma unroll 8
    for (int k = 0; k < HDIM; ++k) acc += r[k] * w1[k * HDIM + j];
    z[j] = fmaxf(acc, 0.0f);
    __syncthreads();
    if (j < NCLS) {
        float a2 = b2[j];
#pragma unroll 8
        for (int k = 0; k < HDIM; ++k) a2 += z[k] * w2[k * NCLS + j];
        lg[j] = a2;
    }
    __syncthreads();
    if (j < NCLS) {
        float m = -1e30f;
#pragma unroll
        for (int c = 0; c < NCLS; ++c) m = fmaxf(m, lg[c]);
        float s = 0.0f;
#pragma unroll
        for (int c = 0; c < NCLS; ++c) s += expf(lg[c] - m);
        out[g * NCLS + j] = lg[j] - m - logf(s);
    }
}

// ---------------- host side ----------------

extern "C" void kernel_launch(void* const* d_in, const int* in_sizes, int n_in,
                              void* d_out, int out_size, void* d_ws, size_t ws_size,
                              hipStream_t stream) {
    const float* x        = (const float*)d_in[0];
    const float* conv_w   = (const float*)d_in[1];
    const float* conv_b   = (const float*)d_in[2];
    const float* bn_gamma = (const float*)d_in[3];
    const float* bn_beta  = (const float*)d_in[4];
    const float* bn_mean  = (const float*)d_in[5];
    const float* bn_var   = (const float*)d_in[6];
    const float* cls_w1   = (const float*)d_in[7];
    const float* cls_b1   = (const float*)d_in[8];
    const float* cls_w2   = (const float*)d_in[9];
    const float* cls_b2   = (const float*)d_in[10];
    const int* edge_index = (const int*)d_in[11];
    const int* batch      = (const int*)d_in[12];
    float* out = (float*)d_out;

    char* ws = (char*)d_ws;
    unsigned* cursor  = (unsigned*)(ws);                  // 256 KiB
    float*    dis     = (float*)(ws + (256u << 10));      // 256 KiB
    unsigned* offsets = (unsigned*)(ws + (512u << 10));   // 256 KiB + 4
    unsigned* bsum    = (unsigned*)(ws + (832u << 10));   // 1 KiB
    unsigned* carry   = (unsigned*)(ws + (833u << 10));   // 1 KiB
    int*      srcs    = (int*)(ws + (2u << 20));          // 4 MiB (src only)
    float*    t       = (float*)(ws + (10u << 20));       // 16 MiB
    float*    h       = (float*)(ws + (26u << 20));       // 16 MiB
    float*    repr    = (float*)(ws + (42u << 20));       // 64 KiB
    __half*   g16     = (__half*)(ws + (43u << 20));      // 8 MiB

    // ---- preprocessing (CSR by dst) ----
    hipMemsetAsync(cursor, 0, N_NODES * sizeof(unsigned), stream);
    deg_count_kernel<<<N_EDGES / 256, 256, 0, stream>>>(edge_index + N_EDGES, cursor);
    scan1_kernel<<<N_NODES / 256, 256, 0, stream>>>(cursor, offsets, bsum, dis);
    scan2_kernel<<<1, 256, 0, stream>>>(bsum, carry, offsets);
    scan3_kernel<<<N_NODES / 256, 256, 0, stream>>>(offsets, carry);
    hipMemsetAsync(cursor, 0, N_NODES * sizeof(unsigned), stream);
    fill_kernel<<<N_EDGES / 256, 256, 0, stream>>>(edge_index, offsets, cursor, srcs);
    cast_kernel<<<(N_NODES * 16) / 256, 256, 0, stream>>>(x, dis, g16);

    // ---- layers ----
    for (int l = 0; l < NLAYER; ++l) {
        const float* hin32 = (l == 0) ? x : h;
        aggregate_kernel<<<(N_NODES * 64) / 256, 256, 0, stream>>>(g16, hin32, dis, offsets, srcs, t);
        gemm_kernel<<<N_NODES / 64, 256, 0, stream>>>(
            t, conv_w + l * HDIM * HDIM, conv_b + l * HDIM,
            bn_gamma + l * HDIM, bn_beta + l * HDIM,
            bn_mean + l * HDIM, bn_var + l * HDIM, dis, h, g16, (l > 0) ? 1 : 0);
    }

    pool_kernel<<<NGRAPH, 256, 0, stream>>>(h, batch, repr);
    classify_kernel<<<NGRAPH, 64, 0, stream>>>(repr, cls_w1, cls_b1, cls_w2, cls_b2, out);
}

// Round 8
// 247.241 us; speedup vs baseline: 1.3367x; 1.3367x over previous
//
#include <hip/hip_runtime.h>
#include <hip/hip_fp16.h>
#include <math.h>

#define N_NODES 65536
#define N_EDGES 1048576
#define HDIM 64
#define NCLS 10
#define NGRAPH 256
#define NLAYER 3
#define BN_EPS 1e-5f
#define NBUCKET 256     // nodes per bucket = 256, bucket = dst >> 8
#define NPBLK 256       // pass-1 blocks; edges per block = 4096

// ---------------- pass 1a: per-block bucket histogram ----------------

__global__ __launch_bounds__(256) void hist_kernel(const int* __restrict__ dst,
                                                   unsigned* __restrict__ bhist) {
    __shared__ unsigned hist[NBUCKET];
    int b = blockIdx.x, tid = threadIdx.x;
    hist[tid] = 0;
    __syncthreads();
    int base = b * 4096;
#pragma unroll
    for (int k = 0; k < 16; ++k) {
        int d = dst[base + k * 256 + tid];
        atomicAdd(&hist[d >> 8], 1u);
    }
    __syncthreads();
    bhist[tid * NPBLK + b] = hist[tid];  // bucket-major for lexicographic scan
}

// ---------------- pass 1b: exclusive scan over 64K (bucket, block) counts ----------------

__global__ __launch_bounds__(256) void scan1_kernel(const unsigned* __restrict__ in,
                                                    unsigned* __restrict__ out,
                                                    unsigned* __restrict__ bsum) {
    __shared__ unsigned lds[256];
    int t = threadIdx.x, b = blockIdx.x;
    unsigned v = in[b * 256 + t];
    lds[t] = v;
    __syncthreads();
#pragma unroll
    for (int off = 1; off < 256; off <<= 1) {
        unsigned add = (t >= off) ? lds[t - off] : 0u;
        __syncthreads();
        lds[t] += add;
        __syncthreads();
    }
    out[b * 256 + t] = lds[t] - v;  // exclusive within block
    if (t == 255) bsum[b] = lds[255];
}

__global__ __launch_bounds__(256) void scan2_kernel(const unsigned* __restrict__ bsum,
                                                    unsigned* __restrict__ carry) {
    __shared__ unsigned lds[256];
    int t = threadIdx.x;
    unsigned v = bsum[t];
    lds[t] = v;
    __syncthreads();
#pragma unroll
    for (int off = 1; off < 256; off <<= 1) {
        unsigned add = (t >= off) ? lds[t - off] : 0u;
        __syncthreads();
        lds[t] += add;
        __syncthreads();
    }
    carry[t] = lds[t] - v;  // exclusive
}

__global__ __launch_bounds__(256) void scan3_kernel(unsigned* __restrict__ out,
                                                    const unsigned* __restrict__ carry) {
    int i = blockIdx.x * 256 + threadIdx.x;
    out[i] += carry[i >> 8];
}

// ---------------- pass 1c: partition edges into coarse buckets (coalesced-ish) ----------------

__global__ __launch_bounds__(256) void partition_kernel(const int* __restrict__ ei,
                                                        const unsigned* __restrict__ bpos,
                                                        int2* __restrict__ ebuf) {
    __shared__ unsigned cur[NBUCKET];
    int b = blockIdx.x, tid = threadIdx.x;
    cur[tid] = bpos[tid * NPBLK + b];
    __syncthreads();
    int base = b * 4096;
#pragma unroll
    for (int k = 0; k < 16; ++k) {
        int e = base + k * 256 + tid;
        int s = ei[e];
        int d = ei[N_EDGES + e];
        unsigned slot = atomicAdd(&cur[d >> 8], 1u);
        ebuf[slot] = make_int2(s, d);
    }
}

// ---------------- pass 2: per-bucket exact CSR (block-private 16KB window) ----------------

__global__ __launch_bounds__(256) void csr_kernel(const int2* __restrict__ ebuf,
                                                  const unsigned* __restrict__ bpos,
                                                  unsigned* __restrict__ offsets,
                                                  float* __restrict__ dis,
                                                  int* __restrict__ srcs) {
    __shared__ unsigned hist[NBUCKET];
    __shared__ unsigned scn[NBUCKET];
    int B = blockIdx.x, tid = threadIdx.x;
    unsigned start = bpos[B * NPBLK];
    unsigned end = (B == NBUCKET - 1) ? N_EDGES : bpos[(B + 1) * NPBLK];
    hist[tid] = 0;
    __syncthreads();
    for (unsigned e = start + tid; e < end; e += 256)
        atomicAdd(&hist[ebuf[e].y & 255], 1u);
    __syncthreads();
    unsigned v = hist[tid];
    scn[tid] = v;
    __syncthreads();
#pragma unroll
    for (int off = 1; off < 256; off <<= 1) {
        unsigned add = (tid >= off) ? scn[tid - off] : 0u;
        __syncthreads();
        scn[tid] += add;
        __syncthreads();
    }
    unsigned gbase = start + scn[tid] - v;  // global CSR base for local node tid
    int node = B * 256 + tid;
    offsets[node] = gbase;
    dis[node] = rsqrtf((float)(v + 1u));
    if (B == NBUCKET - 1 && tid == 255) offsets[N_NODES] = N_EDGES;
    hist[tid] = gbase;  // reuse as global-slot cursor
    __syncthreads();
    for (unsigned e = start + tid; e < end; e += 256) {
        int2 ed = ebuf[e];
        unsigned slot = atomicAdd(&hist[ed.y & 255], 1u);
        srcs[slot] = ed.x;
    }
}

// ---------------- g16 = fp16(x * dis) cast ----------------

__global__ __launch_bounds__(256) void cast_kernel(const float* __restrict__ x,
                                                   const float* __restrict__ dis,
                                                   __half* __restrict__ g16) {
    int i = blockIdx.x * 256 + threadIdx.x;  // float4 index, N*16 total
    float d = dis[i >> 4];
    float4 v = ((const float4*)x)[i];
    __half2 a = __floats2half2_rn(v.x * d, v.y * d);
    __half2 b = __floats2half2_rn(v.z * d, v.w * d);
    uint2 o;
    o.x = *(unsigned*)&a;
    o.y = *(unsigned*)&b;
    ((uint2*)g16)[i] = o;
}

// ---------------- pull aggregate: t[n] = dis[n]^2*h[n] + dis[n]*sum g16[src] ----------------
// one wave per node; lanes = 4 edge-slots x 16 feature lanes (4 halves each).

__global__ __launch_bounds__(256) void aggregate_kernel(const __half* __restrict__ g16,
                                                        const float* __restrict__ hin32,
                                                        const float* __restrict__ dis,
                                                        const unsigned* __restrict__ offsets,
                                                        const int* __restrict__ srcs,
                                                        float* __restrict__ t) {
    int n = (blockIdx.x * 256 + threadIdx.x) >> 6;
    int lane = threadIdx.x & 63;
    int eslot = lane >> 4;      // 0..3
    int fq = lane & 15;         // 4-half feature chunk index
    int e0 = (int)offsets[n];
    int e1 = (int)offsets[n + 1];

    const uint2* hv = (const uint2*)g16;

    float4 acc = make_float4(0.f, 0.f, 0.f, 0.f);
    int e = e0 + eslot;
    for (; e + 12 < e1; e += 16) {
        int s0 = srcs[e];
        int s1 = srcs[e + 4];
        int s2 = srcs[e + 8];
        int s3 = srcs[e + 12];
        uint2 r0 = hv[((size_t)s0 << 4) + fq];
        uint2 r1 = hv[((size_t)s1 << 4) + fq];
        uint2 r2 = hv[((size_t)s2 << 4) + fq];
        uint2 r3 = hv[((size_t)s3 << 4) + fq];
        {
            float2 lo = __half22float2(*(__half2*)&r0.x);
            float2 hi = __half22float2(*(__half2*)&r0.y);
            acc.x += lo.x; acc.y += lo.y; acc.z += hi.x; acc.w += hi.y;
        }
        {
            float2 lo = __half22float2(*(__half2*)&r1.x);
            float2 hi = __half22float2(*(__half2*)&r1.y);
            acc.x += lo.x; acc.y += lo.y; acc.z += hi.x; acc.w += hi.y;
        }
        {
            float2 lo = __half22float2(*(__half2*)&r2.x);
            float2 hi = __half22float2(*(__half2*)&r2.y);
            acc.x += lo.x; acc.y += lo.y; acc.z += hi.x; acc.w += hi.y;
        }
        {
            float2 lo = __half22float2(*(__half2*)&r3.x);
            float2 hi = __half22float2(*(__half2*)&r3.y);
            acc.x += lo.x; acc.y += lo.y; acc.z += hi.x; acc.w += hi.y;
        }
    }
    for (; e < e1; e += 4) {
        int sa = srcs[e];
        uint2 ra = hv[((size_t)sa << 4) + fq];
        float2 lo = __half22float2(*(__half2*)&ra.x);
        float2 hi = __half22float2(*(__half2*)&ra.y);
        acc.x += lo.x; acc.y += lo.y; acc.z += hi.x; acc.w += hi.y;
    }
    acc.x += __shfl_xor(acc.x, 16); acc.y += __shfl_xor(acc.y, 16);
    acc.z += __shfl_xor(acc.z, 16); acc.w += __shfl_xor(acc.w, 16);
    acc.x += __shfl_xor(acc.x, 32); acc.y += __shfl_xor(acc.y, 32);
    acc.z += __shfl_xor(acc.z, 32); acc.w += __shfl_xor(acc.w, 32);
    if (eslot == 0) {
        float d = dis[n];
        float d2 = d * d;
        float4 sv = *(const float4*)&hin32[(size_t)n * HDIM + (fq << 2)];
        acc.x = acc.x * d + sv.x * d2;
        acc.y = acc.y * d + sv.y * d2;
        acc.z = acc.z * d + sv.z * d2;
        acc.w = acc.w * d + sv.w * d2;
        *(float4*)&t[(size_t)n * HDIM + (fq << 2)] = acc;
    }
}

// ---------------- GEMM t@W fused with bias+BN+ReLU+residual; writes h (f32) + g16 ----------------

__global__ __launch_bounds__(256) void gemm_kernel(const float* __restrict__ tin,
                                                   const float* __restrict__ W,
                                                   const float* __restrict__ bias,
                                                   const float* __restrict__ gamma,
                                                   const float* __restrict__ beta,
                                                   const float* __restrict__ mean,
                                                   const float* __restrict__ var,
                                                   const float* __restrict__ dis,
                                                   float* __restrict__ h,
                                                   __half* __restrict__ g16,
                                                   int has_res) {
    __shared__ float hs[64][68];
    __shared__ float ws[64 * 64];
    int tid = threadIdx.x;
    int row0 = blockIdx.x * 64;

    {
        const float4* Wv = (const float4*)W;
        float4* wsv = (float4*)ws;
#pragma unroll
        for (int i = 0; i < 4; ++i) wsv[tid + i * 256] = Wv[tid + i * 256];
    }
    {
        const float4* Hv = (const float4*)(tin + (size_t)row0 * HDIM);
#pragma unroll
        for (int i = 0; i < 4; ++i) {
            int idx = tid + i * 256;
            int r = idx >> 4;
            int c = (idx & 15) << 2;
            *(float4*)&hs[r][c] = Hv[idx];
        }
    }
    __syncthreads();

    int tx = tid & 15, ty = tid >> 4;
    float acc[4][4] = {};
#pragma unroll
    for (int kq = 0; kq < 16; ++kq) {
        int k = kq * 4;
        float4 a[4], b[4];
#pragma unroll
        for (int i = 0; i < 4; ++i) a[i] = *(const float4*)&hs[ty * 4 + i][k];
#pragma unroll
        for (int kk = 0; kk < 4; ++kk) b[kk] = *(const float4*)&ws[(k + kk) * 64 + tx * 4];
#pragma unroll
        for (int kk = 0; kk < 4; ++kk) {
            float b0 = b[kk].x, b1 = b[kk].y, b2 = b[kk].z, b3 = b[kk].w;
#pragma unroll
            for (int i = 0; i < 4; ++i) {
                float av = (kk == 0) ? a[i].x : (kk == 1) ? a[i].y : (kk == 2) ? a[i].z : a[i].w;
                acc[i][0] += av * b0;
                acc[i][1] += av * b1;
                acc[i][2] += av * b2;
                acc[i][3] += av * b3;
            }
        }
    }

    float4 b4 = ((const float4*)bias)[tx];
    float4 g4 = ((const float4*)gamma)[tx];
    float4 be4 = ((const float4*)beta)[tx];
    float4 m4 = ((const float4*)mean)[tx];
    float4 va4 = ((const float4*)var)[tx];
    float sc0 = g4.x * rsqrtf(va4.x + BN_EPS);
    float sc1 = g4.y * rsqrtf(va4.y + BN_EPS);
    float sc2 = g4.z * rsqrtf(va4.z + BN_EPS);
    float sc3 = g4.w * rsqrtf(va4.w + BN_EPS);
    float sh0 = (b4.x - m4.x) * sc0 + be4.x;
    float sh1 = (b4.y - m4.y) * sc1 + be4.y;
    float sh2 = (b4.z - m4.z) * sc2 + be4.z;
    float sh3 = (b4.w - m4.w) * sc3 + be4.w;

#pragma unroll
    for (int i = 0; i < 4; ++i) {
        int row = row0 + ty * 4 + i;
        float o0 = fmaxf(acc[i][0] * sc0 + sh0, 0.0f);
        float o1 = fmaxf(acc[i][1] * sc1 + sh1, 0.0f);
        float o2 = fmaxf(acc[i][2] * sc2 + sh2, 0.0f);
        float o3 = fmaxf(acc[i][3] * sc3 + sh3, 0.0f);
        if (has_res) {
            float4 r = *(const float4*)&h[(size_t)row * HDIM + tx * 4];
            o0 += r.x; o1 += r.y; o2 += r.z; o3 += r.w;
        }
        *(float4*)&h[(size_t)row * HDIM + tx * 4] = make_float4(o0, o1, o2, o3);
        float dd = dis[row];
        __half2 pa = __floats2half2_rn(o0 * dd, o1 * dd);
        __half2 pb = __floats2half2_rn(o2 * dd, o3 * dd);
        uint2 pk;
        pk.x = *(unsigned*)&pa;
        pk.y = *(unsigned*)&pb;
        *(uint2*)&g16[(size_t)row * HDIM + tx * 4] = pk;
    }
}

// ---------------- global mean pool over sorted batch ----------------

__device__ __forceinline__ int lower_bound_batch(const int* __restrict__ batch, int val) {
    int lo = 0, hi = N_NODES;
    while (lo < hi) {
        int mid = (lo + hi) >> 1;
        if (batch[mid] < val) lo = mid + 1; else hi = mid;
    }
    return lo;
}

__global__ __launch_bounds__(256) void pool_kernel(const float* __restrict__ h,
                                                   const int* __restrict__ batch,
                                                   float* __restrict__ repr) {
    int g = blockIdx.x;
    int start = lower_bound_batch(batch, g);
    int end = lower_bound_batch(batch, g + 1);
    int f = threadIdx.x & 63;
    int grp = threadIdx.x >> 6;
    float s0 = 0.f, s1 = 0.f, s2 = 0.f, s3 = 0.f;
    int n = start + grp;
    for (; n + 12 < end; n += 16) {
        s0 += h[(size_t)n * HDIM + f];
        s1 += h[(size_t)(n + 4) * HDIM + f];
        s2 += h[(size_t)(n + 8) * HDIM + f];
        s3 += h[(size_t)(n + 12) * HDIM + f];
    }
    for (; n < end; n += 4) s0 += h[(size_t)n * HDIM + f];
    float s = (s0 + s1) + (s2 + s3);
    __shared__ float red[4][64];
    red[grp][f] = s;
    __syncthreads();
    if (grp == 0) {
        float tot = red[0][f] + red[1][f] + red[2][f] + red[3][f];
        int cnt = end - start;
        repr[g * HDIM + f] = tot / (float)(cnt > 0 ? cnt : 1);
    }
}

// ---------------- classifier ----------------

__global__ __launch_bounds__(64) void classify_kernel(const float* __restrict__ repr,
                                                      const float* __restrict__ w1,
                                                      const float* __restrict__ b1,
                                                      const float* __restrict__ w2,
                                                      const float* __restrict__ b2,
                                                      float* __restrict__ out) {
    int g = blockIdx.x;
    int j = threadIdx.x;
    __shared__ float r[64], z[64], lg[NCLS];
    r[j] = repr[g * HDIM + j];
    __syncthreads();
    float acc = b1[j];
#pragma unroll 8
    for (int k = 0; k < HDIM; ++k) acc += r[k] * w1[k * HDIM + j];
    z[j] = fmaxf(acc, 0.0f);
    __syncthreads();
    if (j < NCLS) {
        float a2 = b2[j];
#pragma unroll 8
        for (int k = 0; k < HDIM; ++k) a2 += z[k] * w2[k * NCLS + j];
        lg[j] = a2;
    }
    __syncthreads();
    if (j < NCLS) {
        float m = -1e30f;
#pragma unroll
        for (int c = 0; c < NCLS; ++c) m = fmaxf(m, lg[c]);
        float s = 0.0f;
#pragma unroll
        for (int c = 0; c < NCLS; ++c) s += expf(lg[c] - m);
        out[g * NCLS + j] = lg[j] - m - logf(s);
    }
}

// ---------------- host side ----------------

extern "C" void kernel_launch(void* const* d_in, const int* in_sizes, int n_in,
                              void* d_out, int out_size, void* d_ws, size_t ws_size,
                              hipStream_t stream) {
    const float* x        = (const float*)d_in[0];
    const float* conv_w   = (const float*)d_in[1];
    const float* conv_b   = (const float*)d_in[2];
    const float* bn_gamma = (const float*)d_in[3];
    const float* bn_beta  = (const float*)d_in[4];
    const float* bn_mean  = (const float*)d_in[5];
    const float* bn_var   = (const float*)d_in[6];
    const float* cls_w1   = (const float*)d_in[7];
    const float* cls_b1   = (const float*)d_in[8];
    const float* cls_w2   = (const float*)d_in[9];
    const float* cls_b2   = (const float*)d_in[10];
    const int* edge_index = (const int*)d_in[11];
    const int* batch      = (const int*)d_in[12];
    float* out = (float*)d_out;

    char* ws = (char*)d_ws;
    unsigned* bhist   = (unsigned*)(ws);                  // 256 KiB
    unsigned* bpos    = (unsigned*)(ws + (256u << 10));   // 256 KiB
    unsigned* bsum    = (unsigned*)(ws + (512u << 10));   // 1 KiB
    unsigned* carry   = (unsigned*)(ws + (513u << 10));   // 1 KiB
    float*    dis     = (float*)(ws + (768u << 10));      // 256 KiB
    unsigned* offsets = (unsigned*)(ws + (1u << 20));     // 256 KiB + 4
    int2*     ebuf    = (int2*)(ws + (2u << 20));         // 8 MiB (dead after csr)
    float*    t       = (float*)(ws + (2u << 20));        // 16 MiB (aliases ebuf, used after)
    int*      srcs    = (int*)(ws + (18u << 20));         // 4 MiB
    float*    h       = (float*)(ws + (22u << 20));       // 16 MiB
    float*    repr    = (float*)(ws + (38u << 20));       // 64 KiB
    __half*   g16     = (__half*)(ws + (39u << 20));      // 8 MiB

    // ---- preprocessing: deterministic two-level bucket sort into CSR ----
    hist_kernel<<<NPBLK, 256, 0, stream>>>(edge_index + N_EDGES, bhist);
    scan1_kernel<<<(NBUCKET * NPBLK) / 256, 256, 0, stream>>>(bhist, bpos, bsum);
    scan2_kernel<<<1, 256, 0, stream>>>(bsum, carry);
    scan3_kernel<<<(NBUCKET * NPBLK) / 256, 256, 0, stream>>>(bpos, carry);
    partition_kernel<<<NPBLK, 256, 0, stream>>>(edge_index, bpos, ebuf);
    csr_kernel<<<NBUCKET, 256, 0, stream>>>(ebuf, bpos, offsets, dis, srcs);
    cast_kernel<<<(N_NODES * 16) / 256, 256, 0, stream>>>(x, dis, g16);

    // ---- layers ----
    for (int l = 0; l < NLAYER; ++l) {
        const float* hin32 = (l == 0) ? x : h;
        aggregate_kernel<<<(N_NODES * 64) / 256, 256, 0, stream>>>(g16, hin32, dis, offsets, srcs, t);
        gemm_kernel<<<N_NODES / 64, 256, 0, stream>>>(
            t, conv_w + l * HDIM * HDIM, conv_b + l * HDIM,
            bn_gamma + l * HDIM, bn_beta + l * HDIM,
            bn_mean + l * HDIM, bn_var + l * HDIM, dis, h, g16, (l > 0) ? 1 : 0);
    }

    pool_kernel<<<NGRAPH, 256, 0, stream>>>(h, batch, repr);
    classify_kernel<<<NGRAPH, 64, 0, stream>>>(repr, cls_w1, cls_b1, cls_w2, cls_b2, out);
}

// Round 9
// 206.372 us; speedup vs baseline: 1.6014x; 1.1980x over previous
//
#include <hip/hip_runtime.h>
#include <hip/hip_fp16.h>
#include <math.h>

#define N_NODES 65536
#define N_EDGES 1048576
#define HDIM 64
#define NCLS 10
#define NGRAPH 256
#define NLAYER 3
#define BN_EPS 1e-5f
#define NBUCKET 256     // nodes per bucket = 256, bucket = dst >> 8
#define NPBLK 256       // pass-1 blocks; edges per block = 4096

// ---------------- pass 1a: per-block bucket histogram ----------------

__global__ __launch_bounds__(256) void hist_kernel(const int* __restrict__ dst,
                                                   unsigned* __restrict__ bhist) {
    __shared__ unsigned hist[NBUCKET];
    int b = blockIdx.x, tid = threadIdx.x;
    hist[tid] = 0;
    __syncthreads();
    int base = b * 4096;
#pragma unroll
    for (int k = 0; k < 16; ++k) {
        int d = dst[base + k * 256 + tid];
        atomicAdd(&hist[d >> 8], 1u);
    }
    __syncthreads();
    bhist[tid * NPBLK + b] = hist[tid];  // bucket-major for lexicographic scan
}

// ---------------- pass 1b: exclusive scan over 64K (bucket, block) counts ----------------

__global__ __launch_bounds__(256) void scan1_kernel(const unsigned* __restrict__ in,
                                                    unsigned* __restrict__ out,
                                                    unsigned* __restrict__ bsum) {
    __shared__ unsigned lds[256];
    int t = threadIdx.x, b = blockIdx.x;
    unsigned v = in[b * 256 + t];
    lds[t] = v;
    __syncthreads();
#pragma unroll
    for (int off = 1; off < 256; off <<= 1) {
        unsigned add = (t >= off) ? lds[t - off] : 0u;
        __syncthreads();
        lds[t] += add;
        __syncthreads();
    }
    out[b * 256 + t] = lds[t] - v;  // exclusive within block
    if (t == 255) bsum[b] = lds[255];
}

__global__ __launch_bounds__(256) void scan2_kernel(const unsigned* __restrict__ bsum,
                                                    unsigned* __restrict__ carry) {
    __shared__ unsigned lds[256];
    int t = threadIdx.x;
    unsigned v = bsum[t];
    lds[t] = v;
    __syncthreads();
#pragma unroll
    for (int off = 1; off < 256; off <<= 1) {
        unsigned add = (t >= off) ? lds[t - off] : 0u;
        __syncthreads();
        lds[t] += add;
        __syncthreads();
    }
    carry[t] = lds[t] - v;  // exclusive
}

__global__ __launch_bounds__(256) void scan3_kernel(unsigned* __restrict__ out,
                                                    const unsigned* __restrict__ carry) {
    int i = blockIdx.x * 256 + threadIdx.x;
    out[i] += carry[i >> 8];
}

// ---------------- pass 1c: partition edges into coarse buckets ----------------

__global__ __launch_bounds__(256) void partition_kernel(const int* __restrict__ ei,
                                                        const unsigned* __restrict__ bpos,
                                                        int2* __restrict__ ebuf) {
    __shared__ unsigned cur[NBUCKET];
    int b = blockIdx.x, tid = threadIdx.x;
    cur[tid] = bpos[tid * NPBLK + b];
    __syncthreads();
    int base = b * 4096;
#pragma unroll
    for (int k = 0; k < 16; ++k) {
        int e = base + k * 256 + tid;
        int s = ei[e];
        int d = ei[N_EDGES + e];
        unsigned slot = atomicAdd(&cur[d >> 8], 1u);
        ebuf[slot] = make_int2(s, d);
    }
}

// ---------------- pass 2: per-bucket exact CSR (block-private 16KB window) ----------------

__global__ __launch_bounds__(256) void csr_kernel(const int2* __restrict__ ebuf,
                                                  const unsigned* __restrict__ bpos,
                                                  unsigned* __restrict__ offsets,
                                                  float* __restrict__ dis,
                                                  int* __restrict__ srcs) {
    __shared__ unsigned hist[NBUCKET];
    __shared__ unsigned scn[NBUCKET];
    int B = blockIdx.x, tid = threadIdx.x;
    unsigned start = bpos[B * NPBLK];
    unsigned end = (B == NBUCKET - 1) ? N_EDGES : bpos[(B + 1) * NPBLK];
    hist[tid] = 0;
    __syncthreads();
    for (unsigned e = start + tid; e < end; e += 256)
        atomicAdd(&hist[ebuf[e].y & 255], 1u);
    __syncthreads();
    unsigned v = hist[tid];
    scn[tid] = v;
    __syncthreads();
#pragma unroll
    for (int off = 1; off < 256; off <<= 1) {
        unsigned add = (tid >= off) ? scn[tid - off] : 0u;
        __syncthreads();
        scn[tid] += add;
        __syncthreads();
    }
    unsigned gbase = start + scn[tid] - v;  // global CSR base for local node tid
    int node = B * 256 + tid;
    offsets[node] = gbase;
    dis[node] = rsqrtf((float)(v + 1u));
    if (B == NBUCKET - 1 && tid == 255) offsets[N_NODES] = N_EDGES;
    hist[tid] = gbase;  // reuse as global-slot cursor
    __syncthreads();
    for (unsigned e = start + tid; e < end; e += 256) {
        int2 ed = ebuf[e];
        unsigned slot = atomicAdd(&hist[ed.y & 255], 1u);
        srcs[slot] = ed.x;
    }
}

// ---------------- GEMM: hw16[n] = fp16((h @ W)[n] * dis[n]) ----------------

__global__ __launch_bounds__(256) void gemm_kernel(const float* __restrict__ hin,
                                                   const float* __restrict__ W,
                                                   const float* __restrict__ dis,
                                                   __half* __restrict__ hw16) {
    __shared__ float hs[64][68];
    __shared__ float ws[64 * 64];
    int tid = threadIdx.x;
    int row0 = blockIdx.x * 64;

    {
        const float4* Wv = (const float4*)W;
        float4* wsv = (float4*)ws;
#pragma unroll
        for (int i = 0; i < 4; ++i) wsv[tid + i * 256] = Wv[tid + i * 256];
    }
    {
        const float4* Hv = (const float4*)(hin + (size_t)row0 * HDIM);
#pragma unroll
        for (int i = 0; i < 4; ++i) {
            int idx = tid + i * 256;
            int r = idx >> 4;
            int c = (idx & 15) << 2;
            *(float4*)&hs[r][c] = Hv[idx];
        }
    }
    __syncthreads();

    int tx = tid & 15, ty = tid >> 4;
    float acc[4][4] = {};
#pragma unroll
    for (int kq = 0; kq < 16; ++kq) {
        int k = kq * 4;
        float4 a[4], b[4];
#pragma unroll
        for (int i = 0; i < 4; ++i) a[i] = *(const float4*)&hs[ty * 4 + i][k];
#pragma unroll
        for (int kk = 0; kk < 4; ++kk) b[kk] = *(const float4*)&ws[(k + kk) * 64 + tx * 4];
#pragma unroll
        for (int kk = 0; kk < 4; ++kk) {
            float b0 = b[kk].x, b1 = b[kk].y, b2 = b[kk].z, b3 = b[kk].w;
#pragma unroll
            for (int i = 0; i < 4; ++i) {
                float av = (kk == 0) ? a[i].x : (kk == 1) ? a[i].y : (kk == 2) ? a[i].z : a[i].w;
                acc[i][0] += av * b0;
                acc[i][1] += av * b1;
                acc[i][2] += av * b2;
                acc[i][3] += av * b3;
            }
        }
    }

#pragma unroll
    for (int i = 0; i < 4; ++i) {
        int row = row0 + ty * 4 + i;
        float dd = dis[row];
        __half2 pa = __floats2half2_rn(acc[i][0] * dd, acc[i][1] * dd);
        __half2 pb = __floats2half2_rn(acc[i][2] * dd, acc[i][3] * dd);
        uint2 pk;
        pk.x = *(unsigned*)&pa;
        pk.y = *(unsigned*)&pb;
        *(uint2*)&hw16[(size_t)row * HDIM + tx * 4] = pk;
    }
}

// ---------------- aggregate + epilogue: h[n] = relu(sc*(dis[n]*(sum+self)) + sh) [+ h[n]] ----------------
// one wave per node; lanes = 4 edge-slots x 16 feature lanes (4 halves each).

__global__ __launch_bounds__(256) void aggregate_kernel(const __half* __restrict__ hw16,
                                                        const float* __restrict__ dis,
                                                        const unsigned* __restrict__ offsets,
                                                        const int* __restrict__ srcs,
                                                        const float* __restrict__ bias,
                                                        const float* __restrict__ gamma,
                                                        const float* __restrict__ beta,
                                                        const float* __restrict__ mean,
                                                        const float* __restrict__ var,
                                                        float* __restrict__ h,
                                                        int has_res) {
    int n = (blockIdx.x * 256 + threadIdx.x) >> 6;
    int lane = threadIdx.x & 63;
    int eslot = lane >> 4;      // 0..3
    int fq = lane & 15;         // 4-half feature chunk index
    int e0 = (int)offsets[n];
    int e1 = (int)offsets[n + 1];

    const uint2* hv = (const uint2*)hw16;

    float4 acc = make_float4(0.f, 0.f, 0.f, 0.f);
    int e = e0 + eslot;
    for (; e + 12 < e1; e += 16) {
        int s0 = srcs[e];
        int s1 = srcs[e + 4];
        int s2 = srcs[e + 8];
        int s3 = srcs[e + 12];
        uint2 r0 = hv[((size_t)s0 << 4) + fq];
        uint2 r1 = hv[((size_t)s1 << 4) + fq];
        uint2 r2 = hv[((size_t)s2 << 4) + fq];
        uint2 r3 = hv[((size_t)s3 << 4) + fq];
        {
            float2 lo = __half22float2(*(__half2*)&r0.x);
            float2 hi = __half22float2(*(__half2*)&r0.y);
            acc.x += lo.x; acc.y += lo.y; acc.z += hi.x; acc.w += hi.y;
        }
        {
            float2 lo = __half22float2(*(__half2*)&r1.x);
            float2 hi = __half22float2(*(__half2*)&r1.y);
            acc.x += lo.x; acc.y += lo.y; acc.z += hi.x; acc.w += hi.y;
        }
        {
            float2 lo = __half22float2(*(__half2*)&r2.x);
            float2 hi = __half22float2(*(__half2*)&r2.y);
            acc.x += lo.x; acc.y += lo.y; acc.z += hi.x; acc.w += hi.y;
        }
        {
            float2 lo = __half22float2(*(__half2*)&r3.x);
            float2 hi = __half22float2(*(__half2*)&r3.y);
            acc.x += lo.x; acc.y += lo.y; acc.z += hi.x; acc.w += hi.y;
        }
    }
    for (; e < e1; e += 4) {
        int sa = srcs[e];
        uint2 ra = hv[((size_t)sa << 4) + fq];
        float2 lo = __half22float2(*(__half2*)&ra.x);
        float2 hi = __half22float2(*(__half2*)&ra.y);
        acc.x += lo.x; acc.y += lo.y; acc.z += hi.x; acc.w += hi.y;
    }
    acc.x += __shfl_xor(acc.x, 16); acc.y += __shfl_xor(acc.y, 16);
    acc.z += __shfl_xor(acc.z, 16); acc.w += __shfl_xor(acc.w, 16);
    acc.x += __shfl_xor(acc.x, 32); acc.y += __shfl_xor(acc.y, 32);
    acc.z += __shfl_xor(acc.z, 32); acc.w += __shfl_xor(acc.w, 32);
    if (eslot == 0) {
        // self-loop: + own row (hw16 already carries one dis factor)
        uint2 rs = hv[((size_t)n << 4) + fq];
        float2 lo = __half22float2(*(__half2*)&rs.x);
        float2 hi = __half22float2(*(__half2*)&rs.y);
        acc.x += lo.x; acc.y += lo.y; acc.z += hi.x; acc.w += hi.y;
        float d = dis[n];
        acc.x *= d; acc.y *= d; acc.z *= d; acc.w *= d;

        float4 b4 = ((const float4*)bias)[fq];
        float4 g4 = ((const float4*)gamma)[fq];
        float4 be4 = ((const float4*)beta)[fq];
        float4 m4 = ((const float4*)mean)[fq];
        float4 va4 = ((const float4*)var)[fq];
        float sc0 = g4.x * rsqrtf(va4.x + BN_EPS);
        float sc1 = g4.y * rsqrtf(va4.y + BN_EPS);
        float sc2 = g4.z * rsqrtf(va4.z + BN_EPS);
        float sc3 = g4.w * rsqrtf(va4.w + BN_EPS);
        float o0 = fmaxf(acc.x * sc0 + (b4.x - m4.x) * sc0 + be4.x, 0.0f);
        float o1 = fmaxf(acc.y * sc1 + (b4.y - m4.y) * sc1 + be4.y, 0.0f);
        float o2 = fmaxf(acc.z * sc2 + (b4.z - m4.z) * sc2 + be4.z, 0.0f);
        float o3 = fmaxf(acc.w * sc3 + (b4.w - m4.w) * sc3 + be4.w, 0.0f);
        if (has_res) {
            float4 r = *(const float4*)&h[(size_t)n * HDIM + (fq << 2)];
            o0 += r.x; o1 += r.y; o2 += r.z; o3 += r.w;
        }
        *(float4*)&h[(size_t)n * HDIM + (fq << 2)] = make_float4(o0, o1, o2, o3);
    }
}

// ---------------- fused global mean pool + classifier ----------------

__device__ __forceinline__ int lower_bound_batch(const int* __restrict__ batch, int val) {
    int lo = 0, hi = N_NODES;
    while (lo < hi) {
        int mid = (lo + hi) >> 1;
        if (batch[mid] < val) lo = mid + 1; else hi = mid;
    }
    return lo;
}

__global__ __launch_bounds__(256) void pool_classify_kernel(const float* __restrict__ h,
                                                            const int* __restrict__ batch,
                                                            const float* __restrict__ w1,
                                                            const float* __restrict__ b1,
                                                            const float* __restrict__ w2,
                                                            const float* __restrict__ b2,
                                                            float* __restrict__ out) {
    int g = blockIdx.x;
    int tid = threadIdx.x;
    int start = lower_bound_batch(batch, g);
    int end = lower_bound_batch(batch, g + 1);
    int f = tid & 63;
    int grp = tid >> 6;
    float s0 = 0.f, s1 = 0.f, s2 = 0.f, s3 = 0.f;
    int n = start + grp;
    for (; n + 12 < end; n += 16) {
        s0 += h[(size_t)n * HDIM + f];
        s1 += h[(size_t)(n + 4) * HDIM + f];
        s2 += h[(size_t)(n + 8) * HDIM + f];
        s3 += h[(size_t)(n + 12) * HDIM + f];
    }
    for (; n < end; n += 4) s0 += h[(size_t)n * HDIM + f];
    float s = (s0 + s1) + (s2 + s3);
    __shared__ float red[4][64];
    __shared__ float repr[64], z[64], lg[NCLS];
    red[grp][f] = s;
    __syncthreads();
    if (grp == 0) {
        float tot = red[0][f] + red[1][f] + red[2][f] + red[3][f];
        int cnt = end - start;
        repr[f] = tot / (float)(cnt > 0 ? cnt : 1);
    }
    __syncthreads();
    if (tid < 64) {
        float acc = b1[tid];
#pragma unroll 8
        for (int k = 0; k < HDIM; ++k) acc += repr[k] * w1[k * HDIM + tid];
        z[tid] = fmaxf(acc, 0.0f);
    }
    __syncthreads();
    if (tid < NCLS) {
        float a2 = b2[tid];
#pragma unroll 8
        for (int k = 0; k < HDIM; ++k) a2 += z[k] * w2[k * NCLS + tid];
        lg[tid] = a2;
    }
    __syncthreads();
    if (tid < NCLS) {
        float m = -1e30f;
#pragma unroll
        for (int c = 0; c < NCLS; ++c) m = fmaxf(m, lg[c]);
        float sum = 0.0f;
#pragma unroll
        for (int c = 0; c < NCLS; ++c) sum += expf(lg[c] - m);
        out[g * NCLS + tid] = lg[tid] - m - logf(sum);
    }
}

// ---------------- host side ----------------

extern "C" void kernel_launch(void* const* d_in, const int* in_sizes, int n_in,
                              void* d_out, int out_size, void* d_ws, size_t ws_size,
                              hipStream_t stream) {
    const float* x        = (const float*)d_in[0];
    const float* conv_w   = (const float*)d_in[1];
    const float* conv_b   = (const float*)d_in[2];
    const float* bn_gamma = (const float*)d_in[3];
    const float* bn_beta  = (const float*)d_in[4];
    const float* bn_mean  = (const float*)d_in[5];
    const float* bn_var   = (const float*)d_in[6];
    const float* cls_w1   = (const float*)d_in[7];
    const float* cls_b1   = (const float*)d_in[8];
    const float* cls_w2   = (const float*)d_in[9];
    const float* cls_b2   = (const float*)d_in[10];
    const int* edge_index = (const int*)d_in[11];
    const int* batch      = (const int*)d_in[12];
    float* out = (float*)d_out;

    char* ws = (char*)d_ws;
    unsigned* bhist   = (unsigned*)(ws);                  // 256 KiB
    unsigned* bpos    = (unsigned*)(ws + (256u << 10));   // 256 KiB
    unsigned* bsum    = (unsigned*)(ws + (512u << 10));   // 1 KiB
    unsigned* carry   = (unsigned*)(ws + (513u << 10));   // 1 KiB
    float*    dis     = (float*)(ws + (768u << 10));      // 256 KiB
    unsigned* offsets = (unsigned*)(ws + (1u << 20));     // 256 KiB + 4
    int2*     ebuf    = (int2*)(ws + (2u << 20));         // 8 MiB (dead after csr)
    int*      srcs    = (int*)(ws + (10u << 20));         // 4 MiB
    __half*   hw16    = (__half*)(ws + (14u << 20));      // 8 MiB
    float*    h       = (float*)(ws + (22u << 20));       // 16 MiB

    // ---- preprocessing: deterministic two-level bucket sort into CSR ----
    hist_kernel<<<NPBLK, 256, 0, stream>>>(edge_index + N_EDGES, bhist);
    scan1_kernel<<<(NBUCKET * NPBLK) / 256, 256, 0, stream>>>(bhist, bpos, bsum);
    scan2_kernel<<<1, 256, 0, stream>>>(bsum, carry);
    scan3_kernel<<<(NBUCKET * NPBLK) / 256, 256, 0, stream>>>(bpos, carry);
    partition_kernel<<<NPBLK, 256, 0, stream>>>(edge_index, bpos, ebuf);
    csr_kernel<<<NBUCKET, 256, 0, stream>>>(ebuf, bpos, offsets, dis, srcs);

    // ---- layers: GEMM first (hw16 = (h@W)*dis in fp16), then gather + epilogue ----
    for (int l = 0; l < NLAYER; ++l) {
        const float* hin = (l == 0) ? x : h;
        gemm_kernel<<<N_NODES / 64, 256, 0, stream>>>(hin, conv_w + l * HDIM * HDIM, dis, hw16);
        aggregate_kernel<<<(N_NODES * 64) / 256, 256, 0, stream>>>(
            hw16, dis, offsets, srcs,
            conv_b + l * HDIM, bn_gamma + l * HDIM, bn_beta + l * HDIM,
            bn_mean + l * HDIM, bn_var + l * HDIM, h, (l > 0) ? 1 : 0);
    }

    pool_classify_kernel<<<NGRAPH, 256, 0, stream>>>(h, batch, cls_w1, cls_b1, cls_w2, cls_b2, out);
}

// Round 10
// 191.419 us; speedup vs baseline: 1.7265x; 1.0781x over previous
//
#include <hip/hip_runtime.h>
#include <hip/hip_fp16.h>
#include <math.h>

#define N_NODES 65536
#define N_EDGES 1048576
#define HDIM 64
#define NCLS 10
#define NGRAPH 256
#define NLAYER 3
#define BN_EPS 1e-5f
#define NBUCKET 256     // nodes per bucket = 256, bucket = dst >> 8
#define NPBLK 256       // pass-1 blocks; edges per block = 4096

// ---------------- pass 1a: per-block bucket histogram ----------------

__global__ __launch_bounds__(256) void hist_kernel(const int* __restrict__ dst,
                                                   unsigned* __restrict__ bhist) {
    __shared__ unsigned hist[NBUCKET];
    int b = blockIdx.x, tid = threadIdx.x;
    hist[tid] = 0;
    __syncthreads();
    int base = b * 4096;
#pragma unroll
    for (int k = 0; k < 16; ++k) {
        int d = dst[base + k * 256 + tid];
        atomicAdd(&hist[d >> 8], 1u);
    }
    __syncthreads();
    bhist[tid * NPBLK + b] = hist[tid];  // bucket-major for lexicographic scan
}

// ---------------- pass 1b: exclusive scan over 64K (bucket, block) counts ----------------

__global__ __launch_bounds__(256) void scan1_kernel(const unsigned* __restrict__ in,
                                                    unsigned* __restrict__ out,
                                                    unsigned* __restrict__ bsum) {
    __shared__ unsigned lds[256];
    int t = threadIdx.x, b = blockIdx.x;
    unsigned v = in[b * 256 + t];
    lds[t] = v;
    __syncthreads();
#pragma unroll
    for (int off = 1; off < 256; off <<= 1) {
        unsigned add = (t >= off) ? lds[t - off] : 0u;
        __syncthreads();
        lds[t] += add;
        __syncthreads();
    }
    out[b * 256 + t] = lds[t] - v;  // exclusive within block
    if (t == 255) bsum[b] = lds[255];
}

__global__ __launch_bounds__(256) void scan2_kernel(const unsigned* __restrict__ bsum,
                                                    unsigned* __restrict__ carry) {
    __shared__ unsigned lds[256];
    int t = threadIdx.x;
    unsigned v = bsum[t];
    lds[t] = v;
    __syncthreads();
#pragma unroll
    for (int off = 1; off < 256; off <<= 1) {
        unsigned add = (t >= off) ? lds[t - off] : 0u;
        __syncthreads();
        lds[t] += add;
        __syncthreads();
    }
    carry[t] = lds[t] - v;  // exclusive
}

__global__ __launch_bounds__(256) void scan3_kernel(unsigned* __restrict__ out,
                                                    const unsigned* __restrict__ carry) {
    int i = blockIdx.x * 256 + threadIdx.x;
    out[i] += carry[i >> 8];
}

// ---------------- pass 1c: partition edges into coarse buckets ----------------

__global__ __launch_bounds__(256) void partition_kernel(const int* __restrict__ ei,
                                                        const unsigned* __restrict__ bpos,
                                                        int2* __restrict__ ebuf) {
    __shared__ unsigned cur[NBUCKET];
    int b = blockIdx.x, tid = threadIdx.x;
    cur[tid] = bpos[tid * NPBLK + b];
    __syncthreads();
    int base = b * 4096;
#pragma unroll
    for (int k = 0; k < 16; ++k) {
        int e = base + k * 256 + tid;
        int s = ei[e];
        int d = ei[N_EDGES + e];
        unsigned slot = atomicAdd(&cur[d >> 8], 1u);
        ebuf[slot] = make_int2(s, d);
    }
}

// ---------------- pass 2: per-bucket exact CSR (block-private 16KB window) ----------------

__global__ __launch_bounds__(256) void csr_kernel(const int2* __restrict__ ebuf,
                                                  const unsigned* __restrict__ bpos,
                                                  unsigned* __restrict__ offsets,
                                                  float* __restrict__ dis,
                                                  int* __restrict__ srcs) {
    __shared__ unsigned hist[NBUCKET];
    __shared__ unsigned scn[NBUCKET];
    int B = blockIdx.x, tid = threadIdx.x;
    unsigned start = bpos[B * NPBLK];
    unsigned end = (B == NBUCKET - 1) ? N_EDGES : bpos[(B + 1) * NPBLK];
    hist[tid] = 0;
    __syncthreads();
    for (unsigned e = start + tid; e < end; e += 256)
        atomicAdd(&hist[ebuf[e].y & 255], 1u);
    __syncthreads();
    unsigned v = hist[tid];
    scn[tid] = v;
    __syncthreads();
#pragma unroll
    for (int off = 1; off < 256; off <<= 1) {
        unsigned add = (tid >= off) ? scn[tid - off] : 0u;
        __syncthreads();
        scn[tid] += add;
        __syncthreads();
    }
    unsigned gbase = start + scn[tid] - v;  // global CSR base for local node tid
    int node = B * 256 + tid;
    offsets[node] = gbase;
    dis[node] = rsqrtf((float)(v + 1u));
    if (B == NBUCKET - 1 && tid == 255) offsets[N_NODES] = N_EDGES;
    hist[tid] = gbase;  // reuse as global-slot cursor
    __syncthreads();
    for (unsigned e = start + tid; e < end; e += 256) {
        int2 ed = ebuf[e];
        unsigned slot = atomicAdd(&hist[ed.y & 255], 1u);
        srcs[slot] = ed.x;
    }
}

// ---------------- BN affine precompute: sc = gamma*rsqrt(var+eps), sh = (bias-mean)*sc+beta ----

__global__ __launch_bounds__(256) void prep_bn_kernel(const float* __restrict__ bias,
                                                      const float* __restrict__ gamma,
                                                      const float* __restrict__ beta,
                                                      const float* __restrict__ mean,
                                                      const float* __restrict__ var,
                                                      float* __restrict__ scb,
                                                      float* __restrict__ shb) {
    int t = threadIdx.x;
    if (t < NLAYER * HDIM) {
        float sc = gamma[t] * rsqrtf(var[t] + BN_EPS);
        scb[t] = sc;
        shb[t] = (bias[t] - mean[t]) * sc + beta[t];
    }
}

// ---------------- GEMM: hw16[n] = fp16((h @ W)[n] * dis[n]) ----------------

__global__ __launch_bounds__(256) void gemm_kernel(const float* __restrict__ hin,
                                                   const float* __restrict__ W,
                                                   const float* __restrict__ dis,
                                                   __half* __restrict__ hw16) {
    __shared__ float hs[64][68];
    __shared__ float ws[64 * 64];
    int tid = threadIdx.x;
    int row0 = blockIdx.x * 64;

    {
        const float4* Wv = (const float4*)W;
        float4* wsv = (float4*)ws;
#pragma unroll
        for (int i = 0; i < 4; ++i) wsv[tid + i * 256] = Wv[tid + i * 256];
    }
    {
        const float4* Hv = (const float4*)(hin + (size_t)row0 * HDIM);
#pragma unroll
        for (int i = 0; i < 4; ++i) {
            int idx = tid + i * 256;
            int r = idx >> 4;
            int c = (idx & 15) << 2;
            *(float4*)&hs[r][c] = Hv[idx];
        }
    }
    __syncthreads();

    int tx = tid & 15, ty = tid >> 4;
    float acc[4][4] = {};
#pragma unroll
    for (int kq = 0; kq < 16; ++kq) {
        int k = kq * 4;
        float4 a[4], b[4];
#pragma unroll
        for (int i = 0; i < 4; ++i) a[i] = *(const float4*)&hs[ty * 4 + i][k];
#pragma unroll
        for (int kk = 0; kk < 4; ++kk) b[kk] = *(const float4*)&ws[(k + kk) * 64 + tx * 4];
#pragma unroll
        for (int kk = 0; kk < 4; ++kk) {
            float b0 = b[kk].x, b1 = b[kk].y, b2 = b[kk].z, b3 = b[kk].w;
#pragma unroll
            for (int i = 0; i < 4; ++i) {
                float av = (kk == 0) ? a[i].x : (kk == 1) ? a[i].y : (kk == 2) ? a[i].z : a[i].w;
                acc[i][0] += av * b0;
                acc[i][1] += av * b1;
                acc[i][2] += av * b2;
                acc[i][3] += av * b3;
            }
        }
    }

#pragma unroll
    for (int i = 0; i < 4; ++i) {
        int row = row0 + ty * 4 + i;
        float dd = dis[row];
        __half2 pa = __floats2half2_rn(acc[i][0] * dd, acc[i][1] * dd);
        __half2 pb = __floats2half2_rn(acc[i][2] * dd, acc[i][3] * dd);
        uint2 pk;
        pk.x = *(unsigned*)&pa;
        pk.y = *(unsigned*)&pb;
        *(uint2*)&hw16[(size_t)row * HDIM + tx * 4] = pk;
    }
}

// ---------------- aggregate + epilogue ----------------
// one wave per node; lanes = 8 edge-slots x 8 feature lanes (uint4 = 8 halves each).
// 16 edges in flight per wave with HALF the vmem instructions of the 16x8B layout.

__global__ __launch_bounds__(256) void aggregate_kernel(const __half* __restrict__ hw16,
                                                        const float* __restrict__ dis,
                                                        const unsigned* __restrict__ offsets,
                                                        const int* __restrict__ srcs,
                                                        const float* __restrict__ scb,
                                                        const float* __restrict__ shb,
                                                        float* __restrict__ h,
                                                        int has_res) {
    int n = (blockIdx.x * 256 + threadIdx.x) >> 6;
    int lane = threadIdx.x & 63;
    int eslot = lane >> 3;      // 0..7
    int fl = lane & 7;          // uint4 chunk within the 128B row
    int e0 = (int)offsets[n];
    int e1 = (int)offsets[n + 1];

    const uint4* hv = (const uint4*)hw16;  // 8 uint4 per row

    float4 accA = make_float4(0.f, 0.f, 0.f, 0.f);  // features fl*8+0..3
    float4 accB = make_float4(0.f, 0.f, 0.f, 0.f);  // features fl*8+4..7
    int e = e0 + eslot;
    for (; e + 8 < e1; e += 16) {
        int s0 = srcs[e];
        int s1 = srcs[e + 8];
        uint4 r0 = hv[(size_t)s0 * 8 + fl];
        uint4 r1 = hv[(size_t)s1 * 8 + fl];
        {
            float2 p0 = __half22float2(*(__half2*)&r0.x);
            float2 p1 = __half22float2(*(__half2*)&r0.y);
            float2 p2 = __half22float2(*(__half2*)&r0.z);
            float2 p3 = __half22float2(*(__half2*)&r0.w);
            accA.x += p0.x; accA.y += p0.y; accA.z += p1.x; accA.w += p1.y;
            accB.x += p2.x; accB.y += p2.y; accB.z += p3.x; accB.w += p3.y;
        }
        {
            float2 p0 = __half22float2(*(__half2*)&r1.x);
            float2 p1 = __half22float2(*(__half2*)&r1.y);
            float2 p2 = __half22float2(*(__half2*)&r1.z);
            float2 p3 = __half22float2(*(__half2*)&r1.w);
            accA.x += p0.x; accA.y += p0.y; accA.z += p1.x; accA.w += p1.y;
            accB.x += p2.x; accB.y += p2.y; accB.z += p3.x; accB.w += p3.y;
        }
    }
    if (e < e1) {
        int s0 = srcs[e];
        uint4 r0 = hv[(size_t)s0 * 8 + fl];
        float2 p0 = __half22float2(*(__half2*)&r0.x);
        float2 p1 = __half22float2(*(__half2*)&r0.y);
        float2 p2 = __half22float2(*(__half2*)&r0.z);
        float2 p3 = __half22float2(*(__half2*)&r0.w);
        accA.x += p0.x; accA.y += p0.y; accA.z += p1.x; accA.w += p1.y;
        accB.x += p2.x; accB.y += p2.y; accB.z += p3.x; accB.w += p3.y;
    }
    // reduce across the 8 edge slots (lane xor 8, 16, 32)
#pragma unroll
    for (int m = 8; m <= 32; m <<= 1) {
        accA.x += __shfl_xor(accA.x, m); accA.y += __shfl_xor(accA.y, m);
        accA.z += __shfl_xor(accA.z, m); accA.w += __shfl_xor(accA.w, m);
        accB.x += __shfl_xor(accB.x, m); accB.y += __shfl_xor(accB.y, m);
        accB.z += __shfl_xor(accB.z, m); accB.w += __shfl_xor(accB.w, m);
    }
    if (lane < 8) {
        // self-loop: + own row (hw16 already carries one dis factor)
        uint4 rs = hv[(size_t)n * 8 + fl];
        float2 p0 = __half22float2(*(__half2*)&rs.x);
        float2 p1 = __half22float2(*(__half2*)&rs.y);
        float2 p2 = __half22float2(*(__half2*)&rs.z);
        float2 p3 = __half22float2(*(__half2*)&rs.w);
        accA.x += p0.x; accA.y += p0.y; accA.z += p1.x; accA.w += p1.y;
        accB.x += p2.x; accB.y += p2.y; accB.z += p3.x; accB.w += p3.y;
        float d = dis[n];
        float4 scA = ((const float4*)scb)[fl * 2];
        float4 scB = ((const float4*)scb)[fl * 2 + 1];
        float4 shA = ((const float4*)shb)[fl * 2];
        float4 shB = ((const float4*)shb)[fl * 2 + 1];
        float o0 = fmaxf(accA.x * d * scA.x + shA.x, 0.0f);
        float o1 = fmaxf(accA.y * d * scA.y + shA.y, 0.0f);
        float o2 = fmaxf(accA.z * d * scA.z + shA.z, 0.0f);
        float o3 = fmaxf(accA.w * d * scA.w + shA.w, 0.0f);
        float o4 = fmaxf(accB.x * d * scB.x + shB.x, 0.0f);
        float o5 = fmaxf(accB.y * d * scB.y + shB.y, 0.0f);
        float o6 = fmaxf(accB.z * d * scB.z + shB.z, 0.0f);
        float o7 = fmaxf(accB.w * d * scB.w + shB.w, 0.0f);
        float* hp = &h[(size_t)n * HDIM + fl * 8];
        if (has_res) {
            float4 rA = *(const float4*)hp;
            float4 rB = *(const float4*)(hp + 4);
            o0 += rA.x; o1 += rA.y; o2 += rA.z; o3 += rA.w;
            o4 += rB.x; o5 += rB.y; o6 += rB.z; o7 += rB.w;
        }
        *(float4*)hp = make_float4(o0, o1, o2, o3);
        *(float4*)(hp + 4) = make_float4(o4, o5, o6, o7);
    }
}

// ---------------- fused global mean pool + classifier ----------------

__device__ __forceinline__ int lower_bound_batch(const int* __restrict__ batch, int val) {
    int lo = 0, hi = N_NODES;
    while (lo < hi) {
        int mid = (lo + hi) >> 1;
        if (batch[mid] < val) lo = mid + 1; else hi = mid;
    }
    return lo;
}

__global__ __launch_bounds__(256) void pool_classify_kernel(const float* __restrict__ h,
                                                            const int* __restrict__ batch,
                                                            const float* __restrict__ w1,
                                                            const float* __restrict__ b1,
                                                            const float* __restrict__ w2,
                                                            const float* __restrict__ b2,
                                                            float* __restrict__ out) {
    int g = blockIdx.x;
    int tid = threadIdx.x;
    int start = lower_bound_batch(batch, g);
    int end = lower_bound_batch(batch, g + 1);
    int f = tid & 63;
    int grp = tid >> 6;
    float s0 = 0.f, s1 = 0.f, s2 = 0.f, s3 = 0.f;
    int n = start + grp;
    for (; n + 12 < end; n += 16) {
        s0 += h[(size_t)n * HDIM + f];
        s1 += h[(size_t)(n + 4) * HDIM + f];
        s2 += h[(size_t)(n + 8) * HDIM + f];
        s3 += h[(size_t)(n + 12) * HDIM + f];
    }
    for (; n < end; n += 4) s0 += h[(size_t)n * HDIM + f];
    float s = (s0 + s1) + (s2 + s3);
    __shared__ float red[4][64];
    __shared__ float repr[64], z[64], lg[NCLS];
    red[grp][f] = s;
    __syncthreads();
    if (grp == 0) {
        float tot = red[0][f] + red[1][f] + red[2][f] + red[3][f];
        int cnt = end - start;
        repr[f] = tot / (float)(cnt > 0 ? cnt : 1);
    }
    __syncthreads();
    if (tid < 64) {
        float acc = b1[tid];
#pragma unroll 8
        for (int k = 0; k < HDIM; ++k) acc += repr[k] * w1[k * HDIM + tid];
        z[tid] = fmaxf(acc, 0.0f);
    }
    __syncthreads();
    if (tid < NCLS) {
        float a2 = b2[tid];
#pragma unroll 8
        for (int k = 0; k < HDIM; ++k) a2 += z[k] * w2[k * NCLS + tid];
        lg[tid] = a2;
    }
    __syncthreads();
    if (tid < NCLS) {
        float m = -1e30f;
#pragma unroll
        for (int c = 0; c < NCLS; ++c) m = fmaxf(m, lg[c]);
        float sum = 0.0f;
#pragma unroll
        for (int c = 0; c < NCLS; ++c) sum += expf(lg[c] - m);
        out[g * NCLS + tid] = lg[tid] - m - logf(sum);
    }
}

// ---------------- host side ----------------

extern "C" void kernel_launch(void* const* d_in, const int* in_sizes, int n_in,
                              void* d_out, int out_size, void* d_ws, size_t ws_size,
                              hipStream_t stream) {
    const float* x        = (const float*)d_in[0];
    const float* conv_w   = (const float*)d_in[1];
    const float* conv_b   = (const float*)d_in[2];
    const float* bn_gamma = (const float*)d_in[3];
    const float* bn_beta  = (const float*)d_in[4];
    const float* bn_mean  = (const float*)d_in[5];
    const float* bn_var   = (const float*)d_in[6];
    const float* cls_w1   = (const float*)d_in[7];
    const float* cls_b1   = (const float*)d_in[8];
    const float* cls_w2   = (const float*)d_in[9];
    const float* cls_b2   = (const float*)d_in[10];
    const int* edge_index = (const int*)d_in[11];
    const int* batch      = (const int*)d_in[12];
    float* out = (float*)d_out;

    char* ws = (char*)d_ws;
    unsigned* bhist   = (unsigned*)(ws);                  // 256 KiB
    unsigned* bpos    = (unsigned*)(ws + (256u << 10));   // 256 KiB
    unsigned* bsum    = (unsigned*)(ws + (512u << 10));   // 1 KiB
    unsigned* carry   = (unsigned*)(ws + (513u << 10));   // 1 KiB
    float*    scb     = (float*)(ws + (514u << 10));      // 768 B (3 layers x 64)
    float*    shb     = (float*)(ws + (515u << 10));      // 768 B
    float*    dis     = (float*)(ws + (768u << 10));      // 256 KiB
    unsigned* offsets = (unsigned*)(ws + (1u << 20));     // 256 KiB + 4
    int2*     ebuf    = (int2*)(ws + (2u << 20));         // 8 MiB (dead after csr)
    int*      srcs    = (int*)(ws + (10u << 20));         // 4 MiB
    __half*   hw16    = (__half*)(ws + (14u << 20));      // 8 MiB
    float*    h       = (float*)(ws + (22u << 20));       // 16 MiB

    // ---- preprocessing: deterministic two-level bucket sort into CSR ----
    hist_kernel<<<NPBLK, 256, 0, stream>>>(edge_index + N_EDGES, bhist);
    scan1_kernel<<<(NBUCKET * NPBLK) / 256, 256, 0, stream>>>(bhist, bpos, bsum);
    scan2_kernel<<<1, 256, 0, stream>>>(bsum, carry);
    scan3_kernel<<<(NBUCKET * NPBLK) / 256, 256, 0, stream>>>(bpos, carry);
    partition_kernel<<<NPBLK, 256, 0, stream>>>(edge_index, bpos, ebuf);
    csr_kernel<<<NBUCKET, 256, 0, stream>>>(ebuf, bpos, offsets, dis, srcs);
    prep_bn_kernel<<<1, 256, 0, stream>>>(conv_b, bn_gamma, bn_beta, bn_mean, bn_var, scb, shb);

    // ---- layers: GEMM first (hw16 = (h@W)*dis in fp16), then gather + epilogue ----
    for (int l = 0; l < NLAYER; ++l) {
        const float* hin = (l == 0) ? x : h;
        gemm_kernel<<<N_NODES / 64, 256, 0, stream>>>(hin, conv_w + l * HDIM * HDIM, dis, hw16);
        aggregate_kernel<<<(N_NODES * 64) / 256, 256, 0, stream>>>(
            hw16, dis, offsets, srcs, scb + l * HDIM, shb + l * HDIM, h, (l > 0) ? 1 : 0);
    }

    pool_classify_kernel<<<NGRAPH, 256, 0, stream>>>(h, batch, cls_w1, cls_b1, cls_w2, cls_b2, out);
}